// Round 2
// baseline (451.506 us; speedup 1.0000x reference)
//
#include <hip/hip_runtime.h>
#include <math.h>

#define TOKW 32   // window size
#define DIMS 256  // feature dim

typedef float f4v __attribute__((ext_vector_type(4)));

// One block per 32-token window. 256 threads = 8 threads/token x 32 dims/thread.
// Tokens 8w..8w+7 live in wave w (token = lane bits 3..5), so cross-token
// reductions use shfl butterflies instead of an LDS tile.
__global__ __launch_bounds__(256) void focus_kernel(
    const float* __restrict__ x,
    float* __restrict__ out_mask,
    float* __restrict__ out_comp)
{
    const int tid  = threadIdx.x;
    const int w    = blockIdx.x;
    const int tok  = tid >> 3;        // 0..31 token within window
    const int lt   = tid & 7;         // 0..7 sub-lane within token
    const int wid  = tid >> 6;        // wave 0..3
    const int tw   = tok & 7;         // token index within wave
    const int lane = tid & 63;

    __shared__ float sh_ws[4][DIMS];  // per-wave partial window sums (4 KB)
    __shared__ float sh_bd[5][DIMS];  // normalized boundary rows: [wid]=last tok of wave, [4]=prev-window last (5 KB)
    __shared__ float sh_m[TOKW];      // mean_sim per token

    const long long g0 = (long long)w * TOKW;
    const long long tokbase = (g0 + tok) * (DIMS / 4);
    const float4* xv = (const float4*)x;

    // ---- load token row: 8 float4 per thread (interleaved by lt)
    float4 v[8];
#pragma unroll
    for (int j = 0; j < 8; ++j)
        v[j] = xv[tokbase + lt + 8 * j];

    // prev-window last token row (wave 0 only) — issue load early
    float4 pv = make_float4(0.f, 0.f, 0.f, 0.f);
    if (tid < 64 && w > 0) pv = xv[(g0 - 1) * (DIMS / 4) + tid];

    // ---- per-token L2 norm (reduce over the 8 lanes of this token)
    float ss = 0.f;
#pragma unroll
    for (int j = 0; j < 8; ++j)
        ss += v[j].x * v[j].x + v[j].y * v[j].y + v[j].z * v[j].z + v[j].w * v[j].w;
    ss += __shfl_xor(ss, 1);
    ss += __shfl_xor(ss, 2);
    ss += __shfl_xor(ss, 4);
    const float rn = 1.0f / fmaxf(sqrtf(ss), 1e-12f);

    // ---- normalized copy (registers only)
    float4 t[8];
#pragma unroll
    for (int j = 0; j < 8; ++j) {
        t[j].x = v[j].x * rn; t[j].y = v[j].y * rn;
        t[j].z = v[j].z * rn; t[j].w = v[j].w * rn;
    }

    // boundary row: last token of each wave (needed by next wave's first token)
    if (tw == 7) {
#pragma unroll
        for (int j = 0; j < 8; ++j)
            *(float4*)&sh_bd[wid][4 * (lt + 8 * j)] = t[j];
    }

    // ---- butterfly sum of normalized rows over the wave's 8 tokens (lane bits 3,4,5)
#pragma unroll
    for (int j = 0; j < 8; ++j) {
        t[j].x += __shfl_xor(t[j].x, 8);
        t[j].y += __shfl_xor(t[j].y, 8);
        t[j].z += __shfl_xor(t[j].z, 8);
        t[j].w += __shfl_xor(t[j].w, 8);
    }
#pragma unroll
    for (int j = 0; j < 8; ++j) {
        t[j].x += __shfl_xor(t[j].x, 16);
        t[j].y += __shfl_xor(t[j].y, 16);
        t[j].z += __shfl_xor(t[j].z, 16);
        t[j].w += __shfl_xor(t[j].w, 16);
    }
#pragma unroll
    for (int j = 0; j < 8; ++j) {
        t[j].x += __shfl_xor(t[j].x, 32);
        t[j].y += __shfl_xor(t[j].y, 32);
        t[j].z += __shfl_xor(t[j].z, 32);
        t[j].w += __shfl_xor(t[j].w, 32);
    }
    if (tw == 0) {
#pragma unroll
        for (int j = 0; j < 8; ++j)
            *(float4*)&sh_ws[wid][4 * (lt + 8 * j)] = t[j];
    }

    // ---- wave 0: normalize prev-window boundary row into sh_bd[4]
    if (tid < 64) {
        float ps = pv.x * pv.x + pv.y * pv.y + pv.z * pv.z + pv.w * pv.w;
        ps += __shfl_xor(ps, 1);
        ps += __shfl_xor(ps, 2);
        ps += __shfl_xor(ps, 4);
        ps += __shfl_xor(ps, 8);
        ps += __shfl_xor(ps, 16);
        ps += __shfl_xor(ps, 32);
        const float prn = 1.0f / fmaxf(sqrtf(ps), 1e-12f);
        // w==0: pv is zero -> stores zeros -> sim_adj=0<0.7 -> mask3[0]=true (matches ref)
        *(float4*)&sh_bd[4][tid * 4] =
            make_float4(pv.x * prn, pv.y * prn, pv.z * prn, pv.w * prn);
    }

    __syncthreads();  // barrier 1 of 2

    // ---- mean_sim[tok] = rn/32 * dot(x_tok, s) with s = sum of 4 wave partials
    {
        float dp = 0.f;
#pragma unroll
        for (int j = 0; j < 8; ++j) {
            const int f = 4 * (lt + 8 * j);
            const float4 s0 = *(const float4*)&sh_ws[0][f];
            const float4 s1 = *(const float4*)&sh_ws[1][f];
            const float4 s2 = *(const float4*)&sh_ws[2][f];
            const float4 s3 = *(const float4*)&sh_ws[3][f];
            dp += v[j].x * (s0.x + s1.x + s2.x + s3.x)
                + v[j].y * (s0.y + s1.y + s2.y + s3.y)
                + v[j].z * (s0.z + s1.z + s2.z + s3.z)
                + v[j].w * (s0.w + s1.w + s2.w + s3.w);
        }
        dp += __shfl_xor(dp, 1);
        dp += __shfl_xor(dp, 2);
        dp += __shfl_xor(dp, 4);
        if (lt == 0) sh_m[tok] = dp * rn * (1.0f / 32.0f);
    }

    // ---- adjacent-token dot via lane-8 shuffle (all lanes converged here).
    // For tw>0 the previous token is in this wave at lane-8 (raw values,
    // rescaled by its rn). tw==0 lanes get garbage and are overridden below.
    const float prn_s = __shfl(rn, (lane - 8) & 63);
    float ap = 0.f;
#pragma unroll
    for (int j = 0; j < 8; ++j) {
        const float px = __shfl(v[j].x, (lane - 8) & 63);
        const float py = __shfl(v[j].y, (lane - 8) & 63);
        const float pz = __shfl(v[j].z, (lane - 8) & 63);
        const float pw = __shfl(v[j].w, (lane - 8) & 63);
        ap += px * v[j].x + py * v[j].y + pz * v[j].z + pw * v[j].w;
    }
    float pscale = prn_s;

    __syncthreads();  // barrier 2 of 2 (publishes sh_m)

    // wave-boundary tokens read the (already-normalized) boundary row from LDS
    if (tw == 0) {
        const float* prow = (tok == 0) ? sh_bd[4] : sh_bd[wid - 1];
        ap = 0.f;
#pragma unroll
        for (int j = 0; j < 8; ++j) {
            const float4 p4 = *(const float4*)&prow[4 * (lt + 8 * j)];
            ap += p4.x * v[j].x + p4.y * v[j].y + p4.z * v[j].z + p4.w * v[j].w;
        }
        pscale = 1.0f;
    }

    // ---- window stats (computed redundantly by every thread; broadcast reads)
    float mu = 0.f;
#pragma unroll
    for (int ti = 0; ti < TOKW; ++ti)
        mu += sh_m[ti];
    mu *= (1.0f / 32.0f);

    float var = 0.f;
#pragma unroll
    for (int ti = 0; ti < TOKW; ++ti) {
        float d = sh_m[ti] - mu;
        var += d * d;
    }
    var *= (1.0f / 31.0f);  // ddof=1 (unbiased, matches torch/jnp std)
    const float thr = mu + sqrtf(var);

    int cnt = 0, amin = 0;
    float mmin = sh_m[0];
#pragma unroll
    for (int ti = 0; ti < TOKW; ++ti) {
        float m = sh_m[ti];
        cnt += (m <= thr) ? 1 : 0;
        if (m < mmin) { mmin = m; amin = ti; }  // first-min, matches argmin
    }

    // ---- write mask1 (stage-1 keep mask) as 0.0/1.0
    if (tid < TOKW) {
        bool k = (cnt > 0) ? (sh_m[tid] <= thr) : (tid == amin);
        __builtin_nontemporal_store(k ? 1.0f : 0.0f, out_mask + g0 + tid);
    }

    // ---- finish sim_adj and write compressed = x * mask3 (nontemporal)
    float sim = ap;
    sim += __shfl_xor(sim, 1);
    sim += __shfl_xor(sim, 2);
    sim += __shfl_xor(sim, 4);
    sim *= rn * pscale;
    const float mult = (sim < 0.7f) ? 1.0f : 0.0f;

    f4v* ov = (f4v*)out_comp;
#pragma unroll
    for (int j = 0; j < 8; ++j) {
        f4v o;
        o.x = v[j].x * mult; o.y = v[j].y * mult;
        o.z = v[j].z * mult; o.w = v[j].w * mult;
        __builtin_nontemporal_store(o, ov + tokbase + lt + 8 * j);
    }
}

extern "C" void kernel_launch(void* const* d_in, const int* in_sizes, int n_in,
                              void* d_out, int out_size, void* d_ws, size_t ws_size,
                              hipStream_t stream) {
    const float* x = (const float*)d_in[0];
    const int ND = in_sizes[0];     // N * D
    const int N  = ND / DIMS;       // 262144
    const int nw = N / TOKW;        // 8192 windows

    float* out_mask = (float*)d_out;       // first N floats: mask1 (0/1)
    float* out_comp = out_mask + N;        // then N*D floats: compressed

    focus_kernel<<<nw, 256, 0, stream>>>(x, out_mask, out_comp);
}

// Round 3
// 441.090 us; speedup vs baseline: 1.0236x; 1.0236x over previous
//
#include <hip/hip_runtime.h>
#include <math.h>

#define TOKW 32   // window size
#define DIMS 256  // feature dim
#define WPB  4    // windows per block (software-pipelined)

// One block handles WPB consecutive windows. 256 threads = 8 threads/token x 32
// dims/thread; token = lane bits 3..5 so intra-wave cross-token reductions are
// shfl butterflies. Window i+1's global loads are issued before window i's
// compute so HBM latency hides under the reduce/barrier/dot phases.
__global__ __launch_bounds__(256) void focus_kernel(
    const float* __restrict__ x,
    float* __restrict__ out_mask,
    float* __restrict__ out_comp)
{
    const int tid  = threadIdx.x;
    const int tok  = tid >> 3;        // 0..31 token within window
    const int lt   = tid & 7;         // 0..7 sub-lane within token
    const int wid  = tid >> 6;        // wave 0..3
    const int tw   = tok & 7;         // token index within wave
    const int lane = tid & 63;

    // LDS hazard design:
    //  sh_bd[i][wid]  : normalized last-token row of wave wid, window i. Written
    //                   window i phase A (pre-barrier-1), read window i (wid-1 row)
    //                   and window i+1 (row 3, tok==0 path). Quad-buffered by i ->
    //                   never rewritten within the block -> no WAR race.
    //  sh_ws[i&1][w]  : per-wave partial window sums. Window i reads between its
    //                   two barriers; window i+2's write is separated by window
    //                   i+1's two barriers -> double buffer suffices.
    //  sh_m[i&1]      : mean_sim per token, same double-buffer argument.
    //  sh_prev        : normalized last token of the block's predecessor window
    //                   (global load, used only for i==0).
    __shared__ float sh_ws[2][4][DIMS];    // 8 KB
    __shared__ float sh_bd[WPB][4][DIMS];  // 16 KB
    __shared__ float sh_prev[DIMS];        // 1 KB
    __shared__ float sh_m[2][TOKW];        // 256 B

    const int wbase = blockIdx.x * WPB;
    const float4* xv = (const float4*)x;

    // ---- prologue: load window 0 of this block + predecessor boundary row
    float4 cur[8];
    {
        const long long tb0 = ((long long)wbase * TOKW + tok) * (DIMS / 4);
#pragma unroll
        for (int j = 0; j < 8; ++j)
            cur[j] = xv[tb0 + lt + 8 * j];
    }
    float4 pv = make_float4(0.f, 0.f, 0.f, 0.f);
    if (tid < 64 && wbase > 0)
        pv = xv[((long long)wbase * TOKW - 1) * (DIMS / 4) + tid];

#pragma unroll
    for (int i = 0; i < WPB; ++i) {
        const int b = i & 1;
        const long long g0 = (long long)(wbase + i) * TOKW;
        const long long tokbase = (g0 + tok) * (DIMS / 4);

        // ---- issue next window's loads first (latency hides under compute)
        float4 nxt[8];
        if (i + 1 < WPB) {
            const long long tbn = tokbase + TOKW * (DIMS / 4);
#pragma unroll
            for (int j = 0; j < 8; ++j)
                nxt[j] = xv[tbn + lt + 8 * j];
        }

        // ---- per-token L2 norm (reduce over the 8 lanes of this token)
        float ss = 0.f;
#pragma unroll
        for (int j = 0; j < 8; ++j)
            ss += cur[j].x * cur[j].x + cur[j].y * cur[j].y
                + cur[j].z * cur[j].z + cur[j].w * cur[j].w;
        ss += __shfl_xor(ss, 1);
        ss += __shfl_xor(ss, 2);
        ss += __shfl_xor(ss, 4);
        const float rn = 1.0f / fmaxf(sqrtf(ss), 1e-12f);

        // ---- normalized copy; publish wave-boundary row
        float4 t[8];
#pragma unroll
        for (int j = 0; j < 8; ++j) {
            t[j].x = cur[j].x * rn; t[j].y = cur[j].y * rn;
            t[j].z = cur[j].z * rn; t[j].w = cur[j].w * rn;
        }
        if (tw == 7) {
#pragma unroll
            for (int j = 0; j < 8; ++j)
                *(float4*)&sh_bd[i][wid][4 * (lt + 8 * j)] = t[j];
        }

        // ---- butterfly sum of normalized rows over the wave's 8 tokens
#pragma unroll
        for (int j = 0; j < 8; ++j) {
            t[j].x += __shfl_xor(t[j].x, 8);
            t[j].y += __shfl_xor(t[j].y, 8);
            t[j].z += __shfl_xor(t[j].z, 8);
            t[j].w += __shfl_xor(t[j].w, 8);
        }
#pragma unroll
        for (int j = 0; j < 8; ++j) {
            t[j].x += __shfl_xor(t[j].x, 16);
            t[j].y += __shfl_xor(t[j].y, 16);
            t[j].z += __shfl_xor(t[j].z, 16);
            t[j].w += __shfl_xor(t[j].w, 16);
        }
#pragma unroll
        for (int j = 0; j < 8; ++j) {
            t[j].x += __shfl_xor(t[j].x, 32);
            t[j].y += __shfl_xor(t[j].y, 32);
            t[j].z += __shfl_xor(t[j].z, 32);
            t[j].w += __shfl_xor(t[j].w, 32);
        }
        if (tw == 0) {
#pragma unroll
            for (int j = 0; j < 8; ++j)
                *(float4*)&sh_ws[b][wid][4 * (lt + 8 * j)] = t[j];
        }

        // ---- window 0 only: normalize predecessor boundary row
        if (i == 0 && tid < 64) {
            float ps = pv.x * pv.x + pv.y * pv.y + pv.z * pv.z + pv.w * pv.w;
            ps += __shfl_xor(ps, 1);
            ps += __shfl_xor(ps, 2);
            ps += __shfl_xor(ps, 4);
            ps += __shfl_xor(ps, 8);
            ps += __shfl_xor(ps, 16);
            ps += __shfl_xor(ps, 32);
            const float prn = 1.0f / fmaxf(sqrtf(ps), 1e-12f);
            // wbase==0: pv is zero -> zeros -> sim_adj=0<0.7 -> mask3[0]=true (ref)
            *(float4*)&sh_prev[tid * 4] =
                make_float4(pv.x * prn, pv.y * prn, pv.z * prn, pv.w * prn);
        }

        __syncthreads();  // barrier 1: sh_bd[i], sh_ws[b], sh_prev visible

        // ---- mean_sim[tok] = rn/32 * dot(x_tok, s), s = sum of 4 wave partials
        {
            float dp = 0.f;
#pragma unroll
            for (int j = 0; j < 8; ++j) {
                const int f = 4 * (lt + 8 * j);
                const float4 s0 = *(const float4*)&sh_ws[b][0][f];
                const float4 s1 = *(const float4*)&sh_ws[b][1][f];
                const float4 s2 = *(const float4*)&sh_ws[b][2][f];
                const float4 s3 = *(const float4*)&sh_ws[b][3][f];
                dp += cur[j].x * (s0.x + s1.x + s2.x + s3.x)
                    + cur[j].y * (s0.y + s1.y + s2.y + s3.y)
                    + cur[j].z * (s0.z + s1.z + s2.z + s3.z)
                    + cur[j].w * (s0.w + s1.w + s2.w + s3.w);
            }
            dp += __shfl_xor(dp, 1);
            dp += __shfl_xor(dp, 2);
            dp += __shfl_xor(dp, 4);
            if (lt == 0) sh_m[b][tok] = dp * rn * (1.0f / 32.0f);
        }

        // ---- adjacent-token dot via lane-8 shuffle (tw>0 tokens; tw==0 fixed below)
        const float prn_s = __shfl(rn, (lane - 8) & 63);
        float ap = 0.f;
#pragma unroll
        for (int j = 0; j < 8; ++j) {
            const float px = __shfl(cur[j].x, (lane - 8) & 63);
            const float py = __shfl(cur[j].y, (lane - 8) & 63);
            const float pz = __shfl(cur[j].z, (lane - 8) & 63);
            const float pw = __shfl(cur[j].w, (lane - 8) & 63);
            ap += px * cur[j].x + py * cur[j].y + pz * cur[j].z + pw * cur[j].w;
        }
        float pscale = prn_s;

        __syncthreads();  // barrier 2: sh_m[b] visible

        // wave-boundary tokens read the normalized boundary row from LDS
        if (tw == 0) {
            const float* prow = (tok == 0)
                ? ((i == 0) ? sh_prev : sh_bd[i - 1][3])
                : sh_bd[i][wid - 1];
            ap = 0.f;
#pragma unroll
            for (int j = 0; j < 8; ++j) {
                const float4 p4 = *(const float4*)&prow[4 * (lt + 8 * j)];
                ap += p4.x * cur[j].x + p4.y * cur[j].y
                    + p4.z * cur[j].z + p4.w * cur[j].w;
            }
            pscale = 1.0f;
        }

        // ---- window stats (redundant per-thread; LDS broadcast reads)
        float mu = 0.f;
#pragma unroll
        for (int ti = 0; ti < TOKW; ++ti)
            mu += sh_m[b][ti];
        mu *= (1.0f / 32.0f);

        float var = 0.f;
#pragma unroll
        for (int ti = 0; ti < TOKW; ++ti) {
            float d = sh_m[b][ti] - mu;
            var += d * d;
        }
        var *= (1.0f / 31.0f);  // ddof=1 (unbiased, matches torch/jnp std)
        const float thr = mu + sqrtf(var);

        int cnt = 0, amin = 0;
        float mmin = sh_m[b][0];
#pragma unroll
        for (int ti = 0; ti < TOKW; ++ti) {
            float m = sh_m[b][ti];
            cnt += (m <= thr) ? 1 : 0;
            if (m < mmin) { mmin = m; amin = ti; }  // first-min, matches argmin
        }

        // ---- write mask1 (stage-1 keep mask) as 0.0/1.0
        if (tid < TOKW) {
            bool k = (cnt > 0) ? (sh_m[b][tid] <= thr) : (tid == amin);
            out_mask[g0 + tid] = k ? 1.0f : 0.0f;
        }

        // ---- finish sim_adj; write compressed = x * mask3 (plain stores)
        float sim = ap;
        sim += __shfl_xor(sim, 1);
        sim += __shfl_xor(sim, 2);
        sim += __shfl_xor(sim, 4);
        sim *= rn * pscale;
        const float mult = (sim < 0.7f) ? 1.0f : 0.0f;

        float4* ov = (float4*)out_comp;
#pragma unroll
        for (int j = 0; j < 8; ++j) {
            float4 o = make_float4(cur[j].x * mult, cur[j].y * mult,
                                   cur[j].z * mult, cur[j].w * mult);
            ov[tokbase + lt + 8 * j] = o;
        }

        // ---- rotate pipeline registers
        if (i + 1 < WPB) {
#pragma unroll
            for (int j = 0; j < 8; ++j)
                cur[j] = nxt[j];
        }
    }
}

extern "C" void kernel_launch(void* const* d_in, const int* in_sizes, int n_in,
                              void* d_out, int out_size, void* d_ws, size_t ws_size,
                              hipStream_t stream) {
    const float* x = (const float*)d_in[0];
    const int ND = in_sizes[0];     // N * D
    const int N  = ND / DIMS;       // 262144
    const int nw = N / TOKW;        // 8192 windows
    const int nb = nw / WPB;        // 2048 blocks

    float* out_mask = (float*)d_out;       // first N floats: mask1 (0/1)
    float* out_comp = out_mask + N;        // then N*D floats: compressed

    focus_kernel<<<nb, 256, 0, stream>>>(x, out_mask, out_comp);
}